// Round 19
// baseline (96.099 us; speedup 1.0000x reference)
//
#include <hip/hip_runtime.h>

typedef __attribute__((ext_vector_type(4)))  short bf16x4;   // 4 bf16 = 2 VGPRs
typedef __attribute__((ext_vector_type(16))) float f32x16;   // MFMA 32x32 C/D

#define TPB    256
#define NPTS   8192
#define NB     4
#define TOTPTS (NB * NPTS)        // 32768
#define XWAVE  64                 // x per wave (2 B-frags)
#define XBLK   (4 * XWAVE)        // 256 x per block
#define YTILE  1024               // y per block
#define NTILES (YTILE / 32)       // 32 MFMA tiles
#define GXB    (NPTS / XBLK)      // 32
#define GYB    (NPTS / YTILE)     // 8 y-chunks
#define NSLICE (2 * NB)           // 8 (dir,batch) slices per chunk
#define WS2_FLOATS ((size_t)GYB * NSLICE * NPTS)  // 512K floats = 2 MB
#define NPARTIAL ((2 * TOTPTS) / 64)   // 1024
#define NFBLK  ((2 * TOTPTS) / TPB)    // 256 finalize blocks

// ---------------------------------------------------------------------------
// R19: fuse the scalar reduction into finalize (last-block election).
// Justification: R15 proved R14's failure was the nnmin retune, NOT the
// wrap-counter reduction — retesting it on the now-verified nnmin. Counter
// init without a memset dispatch: nnmin block(0,0,0) zeroes ctrl; the
// nnmin->finalize kernel boundary guarantees visibility (same boundary that
// already carries ws2). Election: ctrl 0 -> 256 increments -> unique last
// block sees old==255. Partials: release-store / acq-rel counter /
// acquire-load, agent scope (R14 pattern, exonerated).
// nnmin body BYTE-IDENTICAL to R18 (passing, 83.3us, absmax 0.0117):
// K=8 mfma_f32_32x32x8bf16_1k, y compensated + hy split, x bf16-rounded
// (finalize uses identically-rounded hx -> d = |xh - y|, err ~0.01 < 0.036),
// asm-pinned v_min3 combine, unroll 2, launch_bounds(256,1), disjoint-slice
// plain stores (no atomics, no init). ~40us of dur is the harness 0xAA
// ws re-poison fill (untouchable).
// ---------------------------------------------------------------------------

__device__ __forceinline__ short bfr(float f) {       // fp32->bf16 RNE
    unsigned u = __float_as_uint(f);
    return (short)((u + 0x7FFFu + ((u >> 16) & 1u)) >> 16);
}
__device__ __forceinline__ float bf2f(short s) {
    return __uint_as_float(((unsigned)(unsigned short)s) << 16);
}

// grid = (GXB, GYB, 2*NB) = (32, 8, 8) = 2048 blocks, 4 waves each.
// Wave owns 64 x (2 B-frags); block stages YTILE=1024 y as A-frags in LDS.
__global__ void __launch_bounds__(TPB, 1) nnmin_mfma(
        const float* __restrict__ T, const float* __restrict__ P,
        float* __restrict__ ws2, unsigned* __restrict__ ctrl)
{
    __shared__ bf16x4 sA[NTILES * 64];   // A-fragments, 16 KB

    // zero the finalize election counter (visible via kernel boundary)
    if (blockIdx.x == 0 && blockIdx.y == 0 && blockIdx.z == 0 &&
        threadIdx.x == 0) ctrl[0] = 0u;

    const int z   = blockIdx.z;
    const int dir = z >> 2;
    const int b   = z & 3;
    const float* Xb = (dir ? P : T) + (size_t)b * NPTS * 3;
    const float* Yb = (dir ? T : P) + (size_t)b * NPTS * 3;
    const int t     = threadIdx.x;
    const int l     = t & 63;          // lane
    const int w     = t >> 6;          // wave id (0..3)
    const int ybase = blockIdx.y * YTILE;
    const int xw    = blockIdx.x * XBLK + w * XWAVE;   // wave's 64 x

    // ---- stage A-fragments: y compensated hi/lo, hy split ----
    for (int p = t; p < YTILE; p += TPB) {
        const float* yp = Yb + (size_t)(ybase + p) * 3;
        float y0 = yp[0], y1 = yp[1], y2 = yp[2];
        short yh0 = bfr(y0); short yl0 = bfr(y0 - bf2f(yh0));
        short yh1 = bfr(y1); short yl1 = bfr(y1 - bf2f(yh1));
        short yh2 = bfr(y2); short yl2 = bfr(y2 - bf2f(yh2));
        float hy  = 0.5f * (y0 * y0 + y1 * y1 + y2 * y2);
        short hyh = bfr(hy); short hyl = bfr(hy - bf2f(hyh));
        int tile = p >> 5, m = p & 31;
        bf16x4 e0 = {yh0, yl0, yh1, yl1};   // k = 0..3  (lanes < 32)
        bf16x4 e1 = {yh2, yl2, hyh, hyl};   // k = 4..7  (lanes >= 32)
        sA[tile * 64 + m]      = e0;
        sA[tile * 64 + 32 + m] = e1;
    }

    // ---- build the wave's 2 B-fragments: x bf16-rounded, negated ----
    const int   kh  = l >> 5;          // which K-half this lane supplies
    const short ONE = 0x3F80;          // bf16(1.0)
    bf16x4 B[2];
#pragma unroll
    for (int f = 0; f < 2; ++f) {
        const float* xp = Xb + (size_t)(xw + f * 32 + (l & 31)) * 3;
        short h0 = bfr(-xp[0]);        // RNE is sign-symmetric
        short h1 = bfr(-xp[1]);
        short h2 = bfr(-xp[2]);
        bf16x4 e;
        if (kh == 0) e = (bf16x4){h0, h0, h1, h1};
        else         e = (bf16x4){h2, h2, ONE, ONE};
        B[f] = e;
    }
    __syncthreads();

    // ---- main loop: 2 ds_read_b64 + 4 MFMA(K=8) + 32 asm min3 ----
    f32x16 zero = {0.f};               // loop-invariant C input
    float rm[2][16];                   // running mins — pinned to arch VGPRs
#pragma unroll
    for (int f = 0; f < 2; ++f)
#pragma unroll
        for (int i = 0; i < 16; ++i) rm[f][i] = 3.0e38f;

#pragma unroll 2                       // bound A-frag hoisting (R9 spilled)
    for (int tl = 0; tl < NTILES; tl += 2) {
        bf16x4 Aa = sA[(tl + 0) * 64 + l];
        bf16x4 Ab = sA[(tl + 1) * 64 + l];
#pragma unroll
        for (int f = 0; f < 2; ++f) {
            f32x16 da = __builtin_amdgcn_mfma_f32_32x32x8bf16_1k(Aa, B[f], zero, 0, 0, 0);
            f32x16 db = __builtin_amdgcn_mfma_f32_32x32x8bf16_1k(Ab, B[f], zero, 0, 0, 0);
#pragma unroll
            for (int i = 0; i < 16; ++i) {
                float ea = da[i], eb = db[i];
                asm("v_min3_f32 %0, %0, %1, %2"
                    : "+v"(rm[f][i]) : "v"(ea), "v"(eb));
            }
        }
    }

    // ---- epilogue: tree-min + cross-half + plain store to own slice ----
    float* o = ws2 + ((size_t)blockIdx.y * NSLICE + z) * NPTS;
#pragma unroll
    for (int f = 0; f < 2; ++f) {
        float v = rm[f][0];
#pragma unroll
        for (int i = 1; i < 16; ++i) v = fminf(v, rm[f][i]);
        v = fminf(v, __shfl_xor(v, 32, 64));   // rows split across lane halves
        if (l < 32) o[xw + f * 32 + l] = v;    // disjoint: no atomics, no init
    }
}

// Min-reduce 8 chunk slices, add hx(ROUNDED x), sqrt; mins_seeds; per-wave
// partial sums; last block (counter election) reduces partials -> out[0].
__global__ void __launch_bounds__(TPB) finalize_kernel(
        const float* __restrict__ ws2,
        const float* __restrict__ T, const float* __restrict__ P,
        float* __restrict__ out, float* __restrict__ partials,
        unsigned* __restrict__ ctrl)
{
    __shared__ int sLast;
    int i   = blockIdx.x * TPB + threadIdx.x;   // 0 .. 2*TOTPTS-1
    int dir = (i >= TOTPTS) ? 1 : 0;            // uniform per block
    int idx = i - dir * TOTPTS;
    int b   = idx >> 13;
    int x   = idx & (NPTS - 1);

    const float* p0 = ws2 + (size_t)(dir * 4 + b) * NPTS + x;
    float m = 3.0e38f;
#pragma unroll
    for (int c = 0; c < GYB; ++c)               // 8 loads from 2MB (L2)
        m = fminf(m, p0[(size_t)c * NSLICE * NPTS]);

    // hx from the SAME bf16 rounding the MFMA B-side used: d = |xh - y|
    const float* xp = (dir ? P : T) + ((size_t)b * NPTS + x) * 3;
    float a0 = bf2f(bfr(xp[0]));
    float a1 = bf2f(bfr(xp[1]));
    float a2 = bf2f(bfr(xp[2]));
    float hx = 0.5f * (a0 * a0 + a1 * a1 + a2 * a2);
    float d  = sqrtf(fmaxf(2.0f * (hx + m), 0.0f));
    if (dir) out[1 + idx] = d;                  // mins_seeds

#pragma unroll
    for (int off = 32; off > 0; off >>= 1)
        d += __shfl_down(d, off, 64);
    if ((threadIdx.x & 63) == 0)
        __hip_atomic_store(&partials[i >> 6], d,
                           __ATOMIC_RELEASE, __HIP_MEMORY_SCOPE_AGENT);
    __syncthreads();

    if (threadIdx.x == 0) {
        // ctrl zeroed by nnmin (prior kernel); 256 increments; unique last
        // block sees old == NFBLK-1.
        unsigned old = __hip_atomic_fetch_add(ctrl, 1u, __ATOMIC_ACQ_REL,
                                              __HIP_MEMORY_SCOPE_AGENT);
        sLast = (old == (unsigned)(NFBLK - 1)) ? 1 : 0;
    }
    __syncthreads();

    if (sLast && threadIdx.x < 64) {            // one wave sums 1024 partials
        int t = threadIdx.x;
        float s = 0.0f;
#pragma unroll
        for (int q = 0; q < NPARTIAL / 64; ++q)
            s += __hip_atomic_load(&partials[t * (NPARTIAL / 64) + q],
                                   __ATOMIC_ACQUIRE, __HIP_MEMORY_SCOPE_AGENT);
#pragma unroll
        for (int off = 32; off > 0; off >>= 1)
            s += __shfl_down(s, off, 64);
        if (t == 0) out[0] = s * (1.0f / (float)TOTPTS);
    }
}

extern "C" void kernel_launch(void* const* d_in, const int* in_sizes, int n_in,
                              void* d_out, int out_size, void* d_ws, size_t ws_size,
                              hipStream_t stream) {
    const float* truep = (const float*)d_in[0];   // [4, 8192, 3] fp32
    const float* predp = (const float*)d_in[1];   // [4, 8192, 3] fp32
    float* out = (float*)d_out;                   // [1 + 32768] fp32

    float*    ws2      = (float*)d_ws;            // 2 MB chunk mins (no init)
    float*    partials = ws2 + WS2_FLOATS;        // 1024 floats (write-first)
    unsigned* ctrl     = (unsigned*)(partials + NPARTIAL);  // zeroed by nnmin

    dim3 grid(GXB, GYB, 2 * NB);                  // (32, 8, 8) = 2048 blocks
    nnmin_mfma<<<grid, TPB, 0, stream>>>(truep, predp, ws2, ctrl);

    finalize_kernel<<<NFBLK, TPB, 0, stream>>>(
        ws2, truep, predp, out, partials, ctrl);
}

// Round 21
// 82.850 us; speedup vs baseline: 1.1599x; 1.1599x over previous
//
#include <hip/hip_runtime.h>

typedef __attribute__((ext_vector_type(4)))  short bf16x4;   // 4 bf16 = 2 VGPRs
typedef __attribute__((ext_vector_type(16))) float f32x16;   // MFMA 32x32 C/D

#define TPB    256
#define NPTS   8192
#define NB     4
#define TOTPTS (NB * NPTS)        // 32768
#define XWAVE  64                 // x per wave (2 B-frags)
#define XBLK   (4 * XWAVE)        // 256 x per block
#define YTILE  1024               // y per block
#define NTILES (YTILE / 32)       // 32 MFMA tiles
#define GXB    (NPTS / XBLK)      // 32
#define GYB    (NPTS / YTILE)     // 8 y-chunks
#define NSLICE (2 * NB)           // 8 (dir,batch) slices per chunk
#define WS2_FLOATS ((size_t)GYB * NSLICE * NPTS)  // 512K floats = 2 MB
#define NPARTIAL ((2 * TOTPTS) / 64)   // 1024

// ---------------------------------------------------------------------------
// FINAL (= R18, the best passing kernel: 83.3us, absmax 0.0117).
// R20 postscript: inline-asm v_mfma with D in arch VGPRs corrupted output
// (compiler hazard recognizer does not protect hand-written MFMA consumers)
// -> builtin MFMA + asm-pinned v_min3 combine is the stable optimum.
// Exhausted levers (each failed twice, independent mechanisms):
//   ILP pipelines: R12 device-abort, R20 hazard corruption.
//   TLP retune (XWAVE=32, lb(256,4)): R14/R15 deterministic corruption.
//   Tile scaling: R13 neutral (stall is per-tile latency, not per-block).
//   Kernel fusion: R4 (~85us fence tax), R19 (+13us coherence tax).
//   Packed fp32: R5/R6 — v_pk_fma_f32 gives no throughput on gfx950.
// Structure: K=8 mfma_f32_32x32x8bf16_1k (we need 8 K-slots: y compensated
// hi/lo + hy split; x bf16-rounded — finalize uses identically-rounded hx so
// d = |xh - y|, err ~0.01 < 0.036 threshold):
//   A (y, M) k: [yh0,yl0, yh1,yl1 | yh2,yl2, hyh,hyl]
//   B (x, N) k: [-xh0,-xh0, -xh1,-xh1 | -xh2,-xh2, 1,1]
// Combine: asm v_min3_f32 (R10: plain fminf -> accvgpr churn; VOP3 cannot
// source AGPRs). unroll 2 (R9: full unroll hoists all ds_reads -> spill).
// launch_bounds(256,1) (R10: cap 128 -> allocator picks AGPR-form rm).
// Disjoint-slice plain stores, no atomics/init (R16). 3 launches: kernel
// boundary is the only cheap cross-XCD flush (R14/R19).
// Budget: ~40us harness 0xAA ws-fill (sunk) + nnmin ~29 (acc-read floor ~13
// + MFMA->VALU stalls at 2 waves/SIMD) + finalize/scalar/gaps ~13.
// ---------------------------------------------------------------------------

__device__ __forceinline__ short bfr(float f) {       // fp32->bf16 RNE
    unsigned u = __float_as_uint(f);
    return (short)((u + 0x7FFFu + ((u >> 16) & 1u)) >> 16);
}
__device__ __forceinline__ float bf2f(short s) {
    return __uint_as_float(((unsigned)(unsigned short)s) << 16);
}

// grid = (GXB, GYB, 2*NB) = (32, 8, 8) = 2048 blocks, 4 waves each.
// Wave owns 64 x (2 B-frags); block stages YTILE=1024 y as A-frags in LDS.
__global__ void __launch_bounds__(TPB, 1) nnmin_mfma(
        const float* __restrict__ T, const float* __restrict__ P,
        float* __restrict__ ws2)
{
    __shared__ bf16x4 sA[NTILES * 64];   // A-fragments, 16 KB

    const int z   = blockIdx.z;
    const int dir = z >> 2;
    const int b   = z & 3;
    const float* Xb = (dir ? P : T) + (size_t)b * NPTS * 3;
    const float* Yb = (dir ? T : P) + (size_t)b * NPTS * 3;
    const int t     = threadIdx.x;
    const int l     = t & 63;          // lane
    const int w     = t >> 6;          // wave id (0..3)
    const int ybase = blockIdx.y * YTILE;
    const int xw    = blockIdx.x * XBLK + w * XWAVE;   // wave's 64 x

    // ---- stage A-fragments: y compensated hi/lo, hy split ----
    for (int p = t; p < YTILE; p += TPB) {
        const float* yp = Yb + (size_t)(ybase + p) * 3;
        float y0 = yp[0], y1 = yp[1], y2 = yp[2];
        short yh0 = bfr(y0); short yl0 = bfr(y0 - bf2f(yh0));
        short yh1 = bfr(y1); short yl1 = bfr(y1 - bf2f(yh1));
        short yh2 = bfr(y2); short yl2 = bfr(y2 - bf2f(yh2));
        float hy  = 0.5f * (y0 * y0 + y1 * y1 + y2 * y2);
        short hyh = bfr(hy); short hyl = bfr(hy - bf2f(hyh));
        int tile = p >> 5, m = p & 31;
        bf16x4 e0 = {yh0, yl0, yh1, yl1};   // k = 0..3  (lanes < 32)
        bf16x4 e1 = {yh2, yl2, hyh, hyl};   // k = 4..7  (lanes >= 32)
        sA[tile * 64 + m]      = e0;
        sA[tile * 64 + 32 + m] = e1;
    }

    // ---- build the wave's 2 B-fragments: x bf16-rounded, negated ----
    const int   kh  = l >> 5;          // which K-half this lane supplies
    const short ONE = 0x3F80;          // bf16(1.0)
    bf16x4 B[2];
#pragma unroll
    for (int f = 0; f < 2; ++f) {
        const float* xp = Xb + (size_t)(xw + f * 32 + (l & 31)) * 3;
        short h0 = bfr(-xp[0]);        // RNE is sign-symmetric
        short h1 = bfr(-xp[1]);
        short h2 = bfr(-xp[2]);
        bf16x4 e;
        if (kh == 0) e = (bf16x4){h0, h0, h1, h1};
        else         e = (bf16x4){h2, h2, ONE, ONE};
        B[f] = e;
    }
    __syncthreads();

    // ---- main loop: 2 ds_read_b64 + 4 MFMA(K=8) + 32 asm min3 ----
    f32x16 zero = {0.f};               // loop-invariant C input
    float rm[2][16];                   // running mins — pinned to arch VGPRs
#pragma unroll
    for (int f = 0; f < 2; ++f)
#pragma unroll
        for (int i = 0; i < 16; ++i) rm[f][i] = 3.0e38f;

#pragma unroll 2                       // bound A-frag hoisting (R9 spilled)
    for (int tl = 0; tl < NTILES; tl += 2) {
        bf16x4 Aa = sA[(tl + 0) * 64 + l];
        bf16x4 Ab = sA[(tl + 1) * 64 + l];
#pragma unroll
        for (int f = 0; f < 2; ++f) {
            f32x16 da = __builtin_amdgcn_mfma_f32_32x32x8bf16_1k(Aa, B[f], zero, 0, 0, 0);
            f32x16 db = __builtin_amdgcn_mfma_f32_32x32x8bf16_1k(Ab, B[f], zero, 0, 0, 0);
#pragma unroll
            for (int i = 0; i < 16; ++i) {
                float ea = da[i], eb = db[i];
                asm("v_min3_f32 %0, %0, %1, %2"
                    : "+v"(rm[f][i]) : "v"(ea), "v"(eb));
            }
        }
    }

    // ---- epilogue: tree-min + cross-half + plain store to own slice ----
    float* o = ws2 + ((size_t)blockIdx.y * NSLICE + z) * NPTS;
#pragma unroll
    for (int f = 0; f < 2; ++f) {
        float v = rm[f][0];
#pragma unroll
        for (int i = 1; i < 16; ++i) v = fminf(v, rm[f][i]);
        v = fminf(v, __shfl_xor(v, 32, 64));   // rows split across lane halves
        if (l < 32) o[xw + f * 32 + l] = v;    // disjoint: no atomics, no init
    }
}

// Min-reduce 8 chunk slices, add hx(ROUNDED x), sqrt; mins_seeds; wave sums.
__global__ void __launch_bounds__(TPB) finalize_kernel(
        const float* __restrict__ ws2,
        const float* __restrict__ T, const float* __restrict__ P,
        float* __restrict__ out, float* __restrict__ partials)
{
    int i   = blockIdx.x * TPB + threadIdx.x;   // 0 .. 2*TOTPTS-1
    int dir = (i >= TOTPTS) ? 1 : 0;            // uniform per block
    int idx = i - dir * TOTPTS;
    int b   = idx >> 13;
    int x   = idx & (NPTS - 1);

    const float* p0 = ws2 + (size_t)(dir * 4 + b) * NPTS + x;
    float m = 3.0e38f;
#pragma unroll
    for (int c = 0; c < GYB; ++c)               // 8 loads from 2MB (L2)
        m = fminf(m, p0[(size_t)c * NSLICE * NPTS]);

    // hx from the SAME bf16 rounding the MFMA B-side used: d = |xh - y|
    const float* xp = (dir ? P : T) + ((size_t)b * NPTS + x) * 3;
    float a0 = bf2f(bfr(xp[0]));
    float a1 = bf2f(bfr(xp[1]));
    float a2 = bf2f(bfr(xp[2]));
    float hx = 0.5f * (a0 * a0 + a1 * a1 + a2 * a2);
    float d  = sqrtf(fmaxf(2.0f * (hx + m), 0.0f));
    if (dir) out[1 + idx] = d;                  // mins_seeds

#pragma unroll
    for (int off = 32; off > 0; off >>= 1)
        d += __shfl_down(d, off, 64);
    if ((threadIdx.x & 63) == 0) partials[i >> 6] = d;
}

// Single-wave final reduction (separate launch: kernel boundary is the only
// cheap reliable cross-XCD flush — R14/R19 lessons).
__global__ void scalar_kernel(const float* __restrict__ partials,
                              float* __restrict__ out) {
    int t = threadIdx.x;                        // 64 threads
    float s = 0.0f;
#pragma unroll
    for (int k = 0; k < NPARTIAL / 64; ++k)
        s += partials[t * (NPARTIAL / 64) + k];
#pragma unroll
    for (int off = 32; off > 0; off >>= 1)
        s += __shfl_down(s, off, 64);
    if (t == 0) out[0] = s * (1.0f / (float)TOTPTS);
}

extern "C" void kernel_launch(void* const* d_in, const int* in_sizes, int n_in,
                              void* d_out, int out_size, void* d_ws, size_t ws_size,
                              hipStream_t stream) {
    const float* truep = (const float*)d_in[0];   // [4, 8192, 3] fp32
    const float* predp = (const float*)d_in[1];   // [4, 8192, 3] fp32
    float* out = (float*)d_out;                   // [1 + 32768] fp32

    float* ws2      = (float*)d_ws;               // 2 MB chunk mins (no init)
    float* partials = ws2 + WS2_FLOATS;           // 1024 floats (write-first)

    dim3 grid(GXB, GYB, 2 * NB);                  // (32, 8, 8) = 2048 blocks
    nnmin_mfma<<<grid, TPB, 0, stream>>>(truep, predp, ws2);

    finalize_kernel<<<(2 * TOTPTS) / TPB, TPB, 0, stream>>>(
        ws2, truep, predp, out, partials);
    scalar_kernel<<<1, 64, 0, stream>>>(partials, out);
}